// Round 7
// baseline (85.899 us; speedup 1.0000x reference)
//
#include <hip/hip_runtime.h>
#include <math.h>

#define H 1024
#define MAXLEN 128
#define VOCAB 50257

#define ROWS_PB 8                                   // projection: rows per block (2 per wave)
#define NB_OUT ((VOCAB + ROWS_PB - 1) / ROWS_PB)    // 6283 blocks
#define NB_GH 768                                   // gh rows: 3072 waves, 1 row/wave
#define NB_K1 (NB_GH + 32)                          // + 32 blocks for 128 attn-logit rows
#define NB_K2 64                                    // combine blocks: 16 rows each
#define NB_SUB ((VOCAB + 1023) / 1024)              // 50 blocks

__device__ inline float wave_reduce_sum(float v) {
    #pragma unroll
    for (int off = 32; off > 0; off >>= 1) v += __shfl_down(v, off);
    return v;  // lane 0 holds the sum
}

__device__ inline float dot4(float4 a, float4 b) {
    return a.x * b.x + a.y * b.y + a.z * b.z + a.w * b.w;
}

// ===== K1: gh = w_hh . h + b_hh  (3072 rows)  AND  attn logits (128 rows) =====
// Both depend only on kernel inputs; run concurrently in one dispatch.
__global__ void k_pre(const int* x, const float* h, const float* emb,
                      const float* W_attn, const float* b_attn,
                      const float* w_hh, const float* b_hh,
                      float* gh, float* logits) {
    const int lane = threadIdx.x & 63, wid = threadIdx.x >> 6;
    const float4* h4 = (const float4*)h;
    if (blockIdx.x < NB_GH) {
        int row = blockIdx.x * 4 + wid;              // 0..3071
        const float4* w4 = (const float4*)(w_hh + (long long)row * H);
        float acc = 0.f;
        #pragma unroll
        for (int i = 0; i < 4; i++) {
            int idx = lane + i * 64;
            acc += dot4(w4[idx], h4[idx]);
        }
        acc = wave_reduce_sum(acc);
        if (lane == 0) gh[row] = acc + b_hh[row];
    } else {
        int row = (blockIdx.x - NB_GH) * 4 + wid;    // 0..127
        const float4* w4 = (const float4*)(W_attn + row * (2 * H));
        const float4* e4 = (const float4*)(emb + (long long)x[0] * H);
        float acc = 0.f;
        #pragma unroll
        for (int i = 0; i < 8; i++) {
            int idx = lane + i * 64;                 // 512 float4 = 2048 floats
            float4 wv = w4[idx];
            float4 cv = (idx < 256) ? e4[idx] : h4[idx - 256];
            acc += dot4(wv, cv);
        }
        acc = wave_reduce_sum(acc);
        if (lane == 0) logits[row] = acc + b_attn[row];
    }
}

// ===== K2: softmax(128) + attn_applied (redundant per block, in LDS) + combine =====
// 64 blocks x 256 threads; block b computes combine rows [b*16, b*16+16).
__global__ void k_sm_combine(const int* x, const float* emb, const float* logits,
                             const float* enc, const float* W_comb, const float* b_comb,
                             float* g_vec, float* out_attn) {
    __shared__ float buf[MAXLEN];
    __shared__ float wsm[MAXLEN];
    __shared__ float attn[H] __attribute__((aligned(16)));
    const int t = threadIdx.x;
    const int lane = t & 63, wid = t >> 6;

    if (t < MAXLEN) buf[t] = logits[t];
    __syncthreads();
    float m = -INFINITY;
    #pragma unroll 8
    for (int k = 0; k < MAXLEN; k++) m = fmaxf(m, buf[k]);
    if (t < MAXLEN) wsm[t] = expf(buf[t] - m);
    __syncthreads();
    float s = 0.f;
    #pragma unroll 8
    for (int k = 0; k < MAXLEN; k++) s += wsm[k];
    const float inv = 1.f / s;

    // attn_applied into LDS: thread t handles columns j = jj*256 + t
    #pragma unroll
    for (int jj = 0; jj < 4; jj++) {
        int j = jj * 256 + t;
        float acc = 0.f;
        #pragma unroll 8
        for (int k = 0; k < MAXLEN; k++) acc += wsm[k] * enc[k * H + j];
        attn[j] = acc * inv;
    }
    if (blockIdx.x == 0 && t < MAXLEN) out_attn[t] = wsm[t] * inv;
    __syncthreads();

    // combine: wave handles 4 rows; row = bid*16 + wid*4 + r
    const float4* e4 = (const float4*)(emb + (long long)x[0] * H);
    const float4* a4 = (const float4*)attn;
    #pragma unroll
    for (int r = 0; r < 4; r++) {
        int row = blockIdx.x * 16 + wid * 4 + r;
        const float4* w4 = (const float4*)(W_comb + (long long)row * (2 * H));
        float acc = 0.f;
        #pragma unroll
        for (int i = 0; i < 8; i++) {
            int idx = lane + i * 64;
            float4 wv = w4[idx];
            float4 cv = (idx < 256) ? e4[idx] : a4[idx - 256];
            acc += dot4(wv, cv);
        }
        acc = wave_reduce_sum(acc);
        if (lane == 0) g_vec[row] = fmaxf(acc + b_comb[row], 0.f);
    }
}

// ===== K3: gi rows j, j+H, j+2H (vs g) + gates -> h_new[j]; one wave per j =====
__global__ void k_gru(const float* g_vec, const float* h, const float* gh,
                      const float* w_ih, const float* b_ih, const float* b_hh_unused,
                      float* h_new) {
    const int lane = threadIdx.x & 63, wid = threadIdx.x >> 6;
    const int j = blockIdx.x * 4 + wid;              // 0..1023
    const float4* g4 = (const float4*)g_vec;
    float4 vg[4];
    #pragma unroll
    for (int i = 0; i < 4; i++) vg[i] = g4[lane + i * 64];

    float a3[3];
    #pragma unroll
    for (int gt = 0; gt < 3; gt++) {
        const float4* wi = (const float4*)(w_ih + (long long)(j + gt * H) * H);
        float acc = 0.f;
        #pragma unroll
        for (int i = 0; i < 4; i++) acc += dot4(wi[lane + i * 64], vg[i]);
        a3[gt] = acc;
    }
    #pragma unroll
    for (int k = 0; k < 3; k++) a3[k] = wave_reduce_sum(a3[k]);
    if (lane == 0) {
        float gi_r = a3[0] + b_ih[j];
        float gi_z = a3[1] + b_ih[j + H];
        float gi_n = a3[2] + b_ih[j + 2 * H];
        float gh_r = gh[j];
        float gh_z = gh[j + H];
        float gh_n = gh[j + 2 * H];
        float r = 1.f / (1.f + expf(-(gi_r + gh_r)));
        float z = 1.f / (1.f + expf(-(gi_z + gh_z)));
        float n = tanhf(gi_n + r * gh_n);
        h_new[j] = (1.f - z) * n + z * h[j];
    }
}

// ===== K4: projection; 2 rows/wave, 8 rows/block + per-block (max,sumexp) =====
__global__ void k_out_matvec(const float* hn, const float* W_out, const float* b_out,
                             float* out, float* pmax, float* psum) {
    const int t = threadIdx.x;
    const int lane = t & 63, wid = t >> 6;
    const int row0 = blockIdx.x * ROWS_PB + wid * 2;
    __shared__ float lm[ROWS_PB];

    const float4* h4 = (const float4*)hn;
    float4 hreg[4];
    #pragma unroll
    for (int i = 0; i < 4; i++) hreg[i] = h4[lane + i * 64];

    float l0 = -INFINITY, l1 = -INFINITY;
    if (row0 + 1 < VOCAB) {
        const float4* w0 = (const float4*)(W_out + (long long)row0 * H);
        const float4* w1 = (const float4*)(W_out + (long long)(row0 + 1) * H);
        float4 a0[4], a1[4];
        #pragma unroll
        for (int i = 0; i < 4; i++) a0[i] = w0[lane + i * 64];
        #pragma unroll
        for (int i = 0; i < 4; i++) a1[i] = w1[lane + i * 64];
        float acc0 = 0.f, acc1 = 0.f;
        #pragma unroll
        for (int i = 0; i < 4; i++) { acc0 += dot4(a0[i], hreg[i]); acc1 += dot4(a1[i], hreg[i]); }
        acc0 = wave_reduce_sum(acc0);
        acc1 = wave_reduce_sum(acc1);
        if (lane == 0) {
            l0 = acc0 + b_out[row0];
            l1 = acc1 + b_out[row0 + 1];
            out[row0] = l0;
            out[row0 + 1] = l1;
        }
    } else {
        for (int r = row0; r < VOCAB && r < row0 + 2; r++) {
            const float4* w4 = (const float4*)(W_out + (long long)r * H);
            float acc = 0.f;
            #pragma unroll
            for (int i = 0; i < 4; i++) acc += dot4(w4[lane + i * 64], hreg[i]);
            acc = wave_reduce_sum(acc);
            if (lane == 0) {
                float lv = acc + b_out[r];
                out[r] = lv;
                if (r == row0) l0 = lv; else l1 = lv;
            }
        }
    }
    if (lane == 0) { lm[wid * 2] = l0; lm[wid * 2 + 1] = l1; }
    __syncthreads();
    if (t == 0) {
        float m = -INFINITY;
        #pragma unroll
        for (int i = 0; i < ROWS_PB; i++) m = fmaxf(m, lm[i]);
        float s = 0.f;
        #pragma unroll
        for (int i = 0; i < ROWS_PB; i++)
            if (lm[i] != -INFINITY) s += expf(lm[i] - m);
        pmax[blockIdx.x] = m;
        psum[blockIdx.x] = s;
    }
}

// ===== K5: every block redundantly merges partials, then subtracts its slice =====
__global__ void k_merge_sub(const float* pmax, const float* psum, float* out) {
    __shared__ float red[16];
    __shared__ float Msh;
    const int t = threadIdx.x;                       // 1024 threads
    const int lane = t & 63, wid = t >> 6;
    float m = -INFINITY;
    for (int i = t; i < NB_OUT; i += 1024) m = fmaxf(m, pmax[i]);
    #pragma unroll
    for (int off = 32; off > 0; off >>= 1) m = fmaxf(m, __shfl_down(m, off));
    if (lane == 0) red[wid] = m;
    __syncthreads();
    if (t == 0) {
        float mm = red[0];
        #pragma unroll
        for (int i = 1; i < 16; i++) mm = fmaxf(mm, red[i]);
        Msh = mm;
    }
    __syncthreads();
    const float M = Msh;
    float s = 0.f;
    for (int i = t; i < NB_OUT; i += 1024) s += psum[i] * expf(pmax[i] - M);
    s = wave_reduce_sum(s);
    __syncthreads();
    if (lane == 0) red[wid] = s;
    __syncthreads();
    if (t == 0) {
        float ss = 0.f;
        #pragma unroll
        for (int i = 0; i < 16; i++) ss += red[i];
        Msh = M + logf(ss);
    }
    __syncthreads();
    const float c = Msh;
    int v = blockIdx.x * 1024 + t;
    if (v < VOCAB) out[v] -= c;
}

extern "C" void kernel_launch(void* const* d_in, const int* in_sizes, int n_in,
                              void* d_out, int out_size, void* d_ws, size_t ws_size,
                              hipStream_t stream) {
    const int*   x     = (const int*)d_in[0];
    const float* h     = (const float*)d_in[1];   // [1,1,H]
    const float* enc   = (const float*)d_in[2];   // [128,H]
    const float* emb   = (const float*)d_in[3];   // [VOCAB,H]
    const float* W_attn= (const float*)d_in[4];   // [128,2H]
    const float* b_attn= (const float*)d_in[5];
    const float* W_comb= (const float*)d_in[6];   // [H,2H]
    const float* b_comb= (const float*)d_in[7];
    const float* w_ih  = (const float*)d_in[8];   // [3H,H]
    const float* w_hh  = (const float*)d_in[9];
    const float* b_ih  = (const float*)d_in[10];
    const float* b_hh  = (const float*)d_in[11];
    const float* W_out = (const float*)d_in[12];  // [VOCAB,H]
    const float* b_out = (const float*)d_in[13];

    float* out      = (float*)d_out;              // [VOCAB] log-probs
    float* out_h    = out + VOCAB;                // [H] h_new
    float* out_attn = out + VOCAB + H;            // [128] attn_w

    float* ws          = (float*)d_ws;
    float* logits128   = ws;            // 128
    float* g_vec       = ws + 256;      // 1024
    float* gh          = ws + 1536;     // 3072
    float* pmax        = ws + 8192;     // 6283
    float* psum        = ws + 16384;    // 6283

    k_pre<<<NB_K1, 256, 0, stream>>>(x, h, emb, W_attn, b_attn, w_hh, b_hh,
                                     gh, logits128);
    k_sm_combine<<<NB_K2, 256, 0, stream>>>(x, emb, logits128, enc,
                                            W_comb, b_comb, g_vec, out_attn);
    k_gru<<<H / 4, 256, 0, stream>>>(g_vec, h, gh, w_ih, b_ih, b_hh, out_h);
    k_out_matvec<<<NB_OUT, 256, 0, stream>>>(out_h, W_out, b_out, out, pmax, psum);
    k_merge_sub<<<NB_SUB, 1024, 0, stream>>>(pmax, psum, out);
}

// Round 8
// 69.289 us; speedup vs baseline: 1.2397x; 1.2397x over previous
//
#include <hip/hip_runtime.h>
#include <math.h>

#define H 1024
#define MAXLEN 128
#define VOCAB 50257

#define ROWS_PB 16                                  // projection: rows per block (4 per wave)
#define NB_OUT ((VOCAB + ROWS_PB - 1) / ROWS_PB)    // 3142 blocks
#define NB_SUB ((VOCAB + 1023) / 1024)              // 50 blocks

__device__ inline float wave_reduce_sum(float v) {
    #pragma unroll
    for (int off = 32; off > 0; off >>= 1) v += __shfl_down(v, off);
    return v;  // lane 0 holds the sum
}

__device__ inline float dot4(float4 a, float4 b) {
    return a.x * b.x + a.y * b.y + a.z * b.z + a.w * b.w;
}

// K1: attn logits; one wave per row, 32 blocks x 256
__global__ void k_attn_logits(const int* x, const float* h, const float* emb,
                              const float* W_attn, const float* b_attn, float* logits) {
    const int lane = threadIdx.x & 63, wid = threadIdx.x >> 6;
    const int row = blockIdx.x * 4 + wid;   // 0..127
    const float4* w4 = (const float4*)(W_attn + row * (2 * H));
    const float4* e4 = (const float4*)(emb + (long long)x[0] * H);
    const float4* h4 = (const float4*)h;
    float acc = 0.f;
    #pragma unroll
    for (int i = 0; i < 8; i++) {
        int idx = lane + i * 64;            // 512 float4 = 2048 floats
        float4 wv = w4[idx];
        float4 cv = (idx < 256) ? e4[idx] : h4[idx - 256];
        acc += dot4(wv, cv);
    }
    acc = wave_reduce_sum(acc);
    if (lane == 0) logits[row] = acc + b_attn[row];
}

// K2: redundant softmax(128) per block + attn_applied[j] = sum_k w[k]*enc[k][j]
// 8 blocks x 256: block b handles columns [b*128, b*128+128)
__global__ void k_attn_sm_apply(const float* logits, const float* enc,
                                float* attn_applied, float* out_attn) {
    __shared__ float buf[MAXLEN];
    __shared__ float wsm[MAXLEN];
    int t = threadIdx.x;
    if (t < MAXLEN) buf[t] = logits[t];
    __syncthreads();
    float m = -INFINITY;
    #pragma unroll 8
    for (int k = 0; k < MAXLEN; k++) m = fmaxf(m, buf[k]);
    if (t < MAXLEN) wsm[t] = expf(buf[t] - m);
    __syncthreads();
    float s = 0.f;
    #pragma unroll 8
    for (int k = 0; k < MAXLEN; k++) s += wsm[k];
    float inv = 1.f / s;
    if (t < MAXLEN) {                        // 128 active threads per block
        int j = blockIdx.x * MAXLEN + t;
        float acc = 0.f;
        #pragma unroll 8
        for (int k = 0; k < MAXLEN; k++) acc += wsm[k] * enc[k * H + j];
        attn_applied[j] = acc * inv;
        if (blockIdx.x == 0) out_attn[t] = wsm[t] * inv;
    }
}

// K3: g[row] = relu(dot(concat(e, attn_applied), W_comb[row]) + b); one wave per row
__global__ void k_combine(const int* x, const float* emb, const float* attn_applied,
                          const float* W_comb, const float* b_comb, float* g) {
    int wid = threadIdx.x >> 6, lane = threadIdx.x & 63;
    int row = blockIdx.x * 4 + wid;
    const float4* w4 = (const float4*)(W_comb + (long long)row * (2 * H));
    const float4* e4 = (const float4*)(emb + (long long)x[0] * H);
    const float4* a4 = (const float4*)attn_applied;
    float acc = 0.f;
    #pragma unroll
    for (int i = 0; i < 8; i++) {
        int idx = lane + i * 64;
        float4 wv = w4[idx];
        float4 cv = (idx < 256) ? e4[idx] : a4[idx - 256];
        acc += dot4(wv, cv);
    }
    acc = wave_reduce_sum(acc);
    if (lane == 0) g[row] = fmaxf(acc + b_comb[row], 0.f);
}

// K4: fused GRU: block j computes all 6 dots + gates -> h_new[j]; 1024 blocks x 256
__global__ void k_gru_fused(const float* g, const float* h,
                            const float* w_ih, const float* w_hh,
                            const float* b_ih, const float* b_hh, float* h_new) {
    const int j = blockIdx.x, t = threadIdx.x;
    const int lane = t & 63, wid = t >> 6;
    __shared__ float red6[4][6];
    const float4* g4 = (const float4*)g;
    const float4* h4 = (const float4*)h;
    float4 vg = g4[t];
    float4 vh = h4[t];
    float a6[6];
    #pragma unroll
    for (int gt = 0; gt < 3; gt++) {
        const float4* wi = (const float4*)(w_ih + (long long)(j + gt * H) * H);
        const float4* wh = (const float4*)(w_hh + (long long)(j + gt * H) * H);
        a6[gt]     = dot4(wi[t], vg);
        a6[3 + gt] = dot4(wh[t], vh);
    }
    #pragma unroll
    for (int k = 0; k < 6; k++) {
        float v = a6[k];
        #pragma unroll
        for (int off = 32; off > 0; off >>= 1) v += __shfl_down(v, off);
        if (lane == 0) red6[wid][k] = v;
    }
    __syncthreads();
    if (t == 0) {
        float d[6];
        #pragma unroll
        for (int k = 0; k < 6; k++)
            d[k] = red6[0][k] + red6[1][k] + red6[2][k] + red6[3][k];
        float gi_r = d[0] + b_ih[j];
        float gi_z = d[1] + b_ih[j + H];
        float gi_n = d[2] + b_ih[j + 2 * H];
        float gh_r = d[3] + b_hh[j];
        float gh_z = d[4] + b_hh[j + H];
        float gh_n = d[5] + b_hh[j + 2 * H];
        float r = 1.f / (1.f + expf(-(gi_r + gh_r)));
        float z = 1.f / (1.f + expf(-(gi_z + gh_z)));
        float n = tanhf(gi_n + r * gh_n);
        h_new[j] = (1.f - z) * n + z * h[j];
    }
}

// K5: projection; 4 rows per wave (16 outstanding float4 loads), 16 rows/block.
__global__ void k_out_matvec(const float* hn, const float* W_out, const float* b_out,
                             float* out, float* pmax, float* psum) {
    const int t = threadIdx.x;
    const int lane = t & 63, wid = t >> 6;
    const int row0 = blockIdx.x * ROWS_PB + wid * 4;
    __shared__ float lm[ROWS_PB];

    const float4* h4 = (const float4*)hn;
    float4 hreg[4];
    #pragma unroll
    for (int i = 0; i < 4; i++) hreg[i] = h4[lane + i * 64];

    float lv[4] = {-INFINITY, -INFINITY, -INFINITY, -INFINITY};
    if (row0 + 3 < VOCAB) {
        float4 a[4][4];
        #pragma unroll
        for (int r = 0; r < 4; r++) {
            const float4* w4 = (const float4*)(W_out + (long long)(row0 + r) * H);
            #pragma unroll
            for (int i = 0; i < 4; i++) a[r][i] = w4[lane + i * 64];
        }
        #pragma unroll
        for (int r = 0; r < 4; r++) {
            float acc = 0.f;
            #pragma unroll
            for (int i = 0; i < 4; i++) acc += dot4(a[r][i], hreg[i]);
            acc = wave_reduce_sum(acc);
            if (lane == 0) {
                lv[r] = acc + b_out[row0 + r];
                out[row0 + r] = lv[r];
            }
        }
    } else {
        for (int r = 0; r < 4; r++) {
            int row = row0 + r;
            if (row >= VOCAB) break;
            const float4* w4 = (const float4*)(W_out + (long long)row * H);
            float acc = 0.f;
            #pragma unroll
            for (int i = 0; i < 4; i++) acc += dot4(w4[lane + i * 64], hreg[i]);
            acc = wave_reduce_sum(acc);
            if (lane == 0) {
                lv[r] = acc + b_out[row];
                out[row] = lv[r];
            }
        }
    }
    if (lane == 0) {
        #pragma unroll
        for (int r = 0; r < 4; r++) lm[wid * 4 + r] = lv[r];
    }
    __syncthreads();
    if (t == 0) {
        float m = -INFINITY;
        #pragma unroll
        for (int i = 0; i < ROWS_PB; i++) m = fmaxf(m, lm[i]);
        float s = 0.f;
        #pragma unroll
        for (int i = 0; i < ROWS_PB; i++)
            if (lm[i] != -INFINITY) s += expf(lm[i] - m);
        pmax[blockIdx.x] = m;
        psum[blockIdx.x] = s;
    }
}

// K6: every block redundantly merges partials, then subtracts its slice
__global__ void k_merge_sub(const float* pmax, const float* psum, float* out) {
    __shared__ float red[16];
    __shared__ float Msh;
    const int t = threadIdx.x;                       // 1024 threads
    const int lane = t & 63, wid = t >> 6;
    float m = -INFINITY;
    for (int i = t; i < NB_OUT; i += 1024) m = fmaxf(m, pmax[i]);
    #pragma unroll
    for (int off = 32; off > 0; off >>= 1) m = fmaxf(m, __shfl_down(m, off));
    if (lane == 0) red[wid] = m;
    __syncthreads();
    if (t == 0) {
        float mm = red[0];
        #pragma unroll
        for (int i = 1; i < 16; i++) mm = fmaxf(mm, red[i]);
        Msh = mm;
    }
    __syncthreads();
    const float M = Msh;
    float s = 0.f;
    for (int i = t; i < NB_OUT; i += 1024) s += psum[i] * expf(pmax[i] - M);
    s = wave_reduce_sum(s);
    __syncthreads();
    if (lane == 0) red[wid] = s;
    __syncthreads();
    if (t == 0) {
        float ss = 0.f;
        #pragma unroll
        for (int i = 0; i < 16; i++) ss += red[i];
        Msh = M + logf(ss);
    }
    __syncthreads();
    const float c = Msh;
    int v = blockIdx.x * 1024 + t;
    if (v < VOCAB) out[v] -= c;
}

extern "C" void kernel_launch(void* const* d_in, const int* in_sizes, int n_in,
                              void* d_out, int out_size, void* d_ws, size_t ws_size,
                              hipStream_t stream) {
    const int*   x     = (const int*)d_in[0];
    const float* h     = (const float*)d_in[1];   // [1,1,H]
    const float* enc   = (const float*)d_in[2];   // [128,H]
    const float* emb   = (const float*)d_in[3];   // [VOCAB,H]
    const float* W_attn= (const float*)d_in[4];   // [128,2H]
    const float* b_attn= (const float*)d_in[5];
    const float* W_comb= (const float*)d_in[6];   // [H,2H]
    const float* b_comb= (const float*)d_in[7];
    const float* w_ih  = (const float*)d_in[8];   // [3H,H]
    const float* w_hh  = (const float*)d_in[9];
    const float* b_ih  = (const float*)d_in[10];
    const float* b_hh  = (const float*)d_in[11];
    const float* W_out = (const float*)d_in[12];  // [VOCAB,H]
    const float* b_out = (const float*)d_in[13];

    float* out      = (float*)d_out;              // [VOCAB] log-probs
    float* out_h    = out + VOCAB;                // [H] h_new
    float* out_attn = out + VOCAB + H;            // [128] attn_w

    float* ws          = (float*)d_ws;
    float* logits128   = ws;            // 128
    float* attn_applied= ws + 256;      // 1024
    float* g_vec       = ws + 1280;     // 1024
    float* pmax        = ws + 4096;     // NB_OUT (3142)
    float* psum        = ws + 12288;    // NB_OUT

    k_attn_logits<<<MAXLEN / 4, 256, 0, stream>>>(x, h, emb, W_attn, b_attn, logits128);
    k_attn_sm_apply<<<H / MAXLEN, 256, 0, stream>>>(logits128, enc, attn_applied, out_attn);
    k_combine<<<H / 4, 256, 0, stream>>>(x, emb, attn_applied, W_comb, b_comb, g_vec);
    k_gru_fused<<<H, 256, 0, stream>>>(g_vec, h, w_ih, w_hh, b_ih, b_hh, out_h);
    k_out_matvec<<<NB_OUT, 256, 0, stream>>>(out_h, W_out, b_out, out, pmax, psum);
    k_merge_sub<<<NB_SUB, 1024, 0, stream>>>(pmax, psum, out);
}